// Round 10
// baseline (143.489 us; speedup 1.0000x reference)
//
#include <hip/hip_runtime.h>
#include <math.h>

#define L_SEQ 1024
#define DDIM  256
#define ADIM  128
#define NB    32

typedef __attribute__((ext_vector_type(8))) short bf16x8;
typedef __attribute__((ext_vector_type(4))) float f32x4;
typedef __attribute__((ext_vector_type(16))) float f32x16;

__device__ __forceinline__ ushort f2bf(float x) {      // fp32 -> bf16 RNE
    uint u = __builtin_bit_cast(uint, x);
    u = (u + 0x7FFFu + ((u >> 16) & 1u)) >> 16;
    return (ushort)u;
}
__device__ __forceinline__ float bf2f(ushort h) {
    uint u = ((uint)h) << 16;
    return __builtin_bit_cast(float, u);
}
// tanh(x) = 1 - 2/(1+e^{2x}); exact at both saturations (inf -> 1, 0 -> -1),
// so no abs/copysign needed: 5 VALU ops (mul, exp, add, rcp, fma).
__device__ __forceinline__ float tanh_fast(float x) {
    float e = __expf(x * 2.0f);
    return fmaf(-2.0f, __builtin_amdgcn_rcpf(1.0f + e), 1.0f);
}
__device__ __forceinline__ uint cvtpk_bf16(float lo, float hi) {
    uint r;
    asm("v_cvt_pk_bf16_f32 %0, %1, %2" : "=v"(r) : "v"(lo), "v"(hi));
    return r;
}
// async global->LDS, 16B per lane; lds_dst wave-uniform, g_src per-lane
__device__ __forceinline__ void async_copy16(ushort* lds_dst, const ushort* g_src) {
    __builtin_amdgcn_global_load_lds(
        (const __attribute__((address_space(1))) unsigned int*)(g_src),
        (__attribute__((address_space(3))) unsigned int*)(lds_dst),
        16, 0, 0);
}
__device__ __forceinline__ void async_copy16f(float* lds_dst, const float* g_src) {
    __builtin_amdgcn_global_load_lds(
        (const __attribute__((address_space(1))) unsigned int*)(g_src),
        (__attribute__((address_space(3))) unsigned int*)(lds_dst),
        16, 0, 0);
}

// ---------------------------------------------------------------------------
// Weight prep: w [256, N] fp32 -> WT_h/WT_l [N, 256] bf16 (transpose + split)
// ---------------------------------------------------------------------------
__global__ __launch_bounds__(256) void wt_prep(
        const float* __restrict__ W,  const float* __restrict__ Wv,
        const float* __restrict__ Wq,
        ushort* __restrict__ WTh, ushort* __restrict__ WvTh,
        ushort* __restrict__ WqTh) {
    int k = blockIdx.x;
    int tid = threadIdx.x;
    #pragma unroll
    for (int t = tid; t < 512; t += 256) {
        const float* src; ushort* dh; int n, nn;
        if (t < 256)      { src = W;  dh = WTh;  n = t;       nn = 256; }
        else if (t < 384) { src = Wv; dh = WvTh; n = t - 256; nn = 128; }
        else              { src = Wq; dh = WqTh; n = t - 384; nn = 128; }
        ushort* dl = dh + (size_t)nn * 256;
        float x = src[(size_t)k * nn + n];
        ushort hh = f2bf(x);
        dh[(size_t)n * 256 + k] = hh;
        dl[(size_t)n * 256 + k] = f2bf(x - bf2f(hh));
    }
}

// ---------------------------------------------------------------------------
// All three projection GEMMs + f2 bf16 convert in one launch.
// Blocks [0,1024): 32x32x16 MFMA GEMM, bf16 hi/lo split (Ah*Bh+Ah*Bl+Al*Bh).
// Blocks [1024,2048): elementwise f2 -> bf16 (fills bandwidth bubbles; only
// the later fused kernel reads f2b, so no ordering hazard).
// ---------------------------------------------------------------------------
__global__ __launch_bounds__(256, 2) void proj_all(
        const float* __restrict__ f1, const float* __restrict__ f2,
        const ushort* __restrict__ WTh, const ushort* __restrict__ WvTh,
        const ushort* __restrict__ WqTh,
        ushort* __restrict__ f1Wb, ushort* __restrict__ f1Wvb,
        ushort* __restrict__ f2Wqb, ushort* __restrict__ f2b) {
    __shared__ float  As[128 * 64];
    __shared__ ushort Bs[128 * 128];

    const int bid = blockIdx.x;
    const int tid = threadIdx.x;

    if (bid >= 1024) {                       // f2 convert path (no barriers)
        const int base = (bid - 1024) * 8192;
        #pragma unroll
        for (int it = 0; it < 4; ++it) {
            int i = base + it * 2048 + tid * 8;
            float4 a = *reinterpret_cast<const float4*>(&f2[i]);
            float4 b = *reinterpret_cast<const float4*>(&f2[i + 4]);
            ushort4 lo = { f2bf(a.x), f2bf(a.y), f2bf(a.z), f2bf(a.w) };
            ushort4 hi = { f2bf(b.x), f2bf(b.y), f2bf(b.z), f2bf(b.w) };
            *reinterpret_cast<ushort4*>(&f2b[i]) = lo;
            *reinterpret_cast<ushort4*>(&f2b[i + 4]) = hi;
        }
        return;
    }

    const float* A; const ushort* BTh; ushort* C; int N, m0, n0;
    if (bid < 512)      { A = f1; BTh = WTh;  C = f1Wb;  N = 256; m0 = (bid >> 1) * 128; n0 = (bid & 1) * 128; }
    else if (bid < 768) { A = f1; BTh = WvTh; C = f1Wvb; N = 128; m0 = (bid - 512) * 128; n0 = 0; }
    else                { A = f2; BTh = WqTh; C = f2Wqb; N = 128; m0 = (bid - 768) * 128; n0 = 0; }

    const int lane = tid & 63;
    const int wid  = tid >> 6;
    const int l31  = lane & 31;
    const int h    = lane >> 5;
    const int wrow = wid * 32;
    const int row  = wrow + l31;
    const int rsw  = row & 15;

    // per-lane staging source offsets (linear dest, inverse-swizzled source)
    int aoff[8], boff[8];
    #pragma unroll
    for (int it = 0; it < 8; ++it) {
        int idx = it * 256 + tid;
        int r   = idx >> 4, g = idx & 15;
        int gx  = g ^ (r & 15);
        aoff[it] = (m0 + r) * 256 + gx * 4;
        boff[it] = (n0 + r) * 256 + (gx & 7) * 8 + ((gx & 8) ? N * 256 : 0);
    }

    f32x16 acc[4];
    #pragma unroll
    for (int i = 0; i < 4; ++i)
        #pragma unroll
        for (int j = 0; j < 16; ++j) acc[i][j] = 0.f;

    for (int kc = 0; kc < 4; ++kc) {
        const int k0 = kc * 64;
        __syncthreads();
        #pragma unroll
        for (int it = 0; it < 8; ++it) {
            async_copy16f(&As[it * 1024 + wid * 256], A + aoff[it] + k0);
            async_copy16(&Bs[it * 2048 + wid * 512], BTh + boff[it] + k0);
        }
        __syncthreads();

        #pragma unroll
        for (int s = 0; s < 4; ++s) {
            int ga = s * 4 + h * 2;
            float4 alo = *reinterpret_cast<const float4*>(&As[(row * 16 + (ga ^ rsw)) * 4]);
            float4 ahi = *reinterpret_cast<const float4*>(&As[(row * 16 + ((ga + 1) ^ rsw)) * 4]);
            uint ah0 = cvtpk_bf16(alo.x, alo.y);
            uint ah1 = cvtpk_bf16(alo.z, alo.w);
            uint ah2 = cvtpk_bf16(ahi.x, ahi.y);
            uint ah3 = cvtpk_bf16(ahi.z, ahi.w);
            float r0 = alo.x - __builtin_bit_cast(float, ah0 << 16);
            float r1 = alo.y - __builtin_bit_cast(float, ah0 & 0xffff0000u);
            float r2 = alo.z - __builtin_bit_cast(float, ah1 << 16);
            float r3 = alo.w - __builtin_bit_cast(float, ah1 & 0xffff0000u);
            float r4 = ahi.x - __builtin_bit_cast(float, ah2 << 16);
            float r5 = ahi.y - __builtin_bit_cast(float, ah2 & 0xffff0000u);
            float r6 = ahi.z - __builtin_bit_cast(float, ah3 << 16);
            float r7 = ahi.w - __builtin_bit_cast(float, ah3 & 0xffff0000u);
            uint al0 = cvtpk_bf16(r0, r1), al1 = cvtpk_bf16(r2, r3);
            uint al2 = cvtpk_bf16(r4, r5), al3 = cvtpk_bf16(r6, r7);
            union { uint u[4]; bf16x8 v; } uh = {{ah0, ah1, ah2, ah3}};
            union { uint u[4]; bf16x8 v; } ul = {{al0, al1, al2, al3}};
            bf16x8 ah = uh.v, al = ul.v;

            #pragma unroll
            for (int nf = 0; nf < 4; ++nf) {
                int col = nf * 32 + l31;
                int csw = col & 15;
                int gb  = s * 2 + h;
                bf16x8 bh = *reinterpret_cast<const bf16x8*>(&Bs[col * 128 + (gb ^ csw) * 8]);
                bf16x8 bl = *reinterpret_cast<const bf16x8*>(&Bs[col * 128 + ((gb + 8) ^ csw) * 8]);
                acc[nf] = __builtin_amdgcn_mfma_f32_32x32x16_bf16(ah, bh, acc[nf], 0, 0, 0);
                acc[nf] = __builtin_amdgcn_mfma_f32_32x32x16_bf16(ah, bl, acc[nf], 0, 0, 0);
                acc[nf] = __builtin_amdgcn_mfma_f32_32x32x16_bf16(al, bh, acc[nf], 0, 0, 0);
            }
        }
    }

    #pragma unroll
    for (int nf = 0; nf < 4; ++nf)
        #pragma unroll
        for (int reg = 0; reg < 16; ++reg) {
            int rowl = (reg & 3) + 8 * (reg >> 2) + 4 * h;
            C[(size_t)(m0 + wrow + rowl) * N + n0 + nf * 32 + l31] = f2bf(acc[nf][reg]);
        }
}

// ---------------------------------------------------------------------------
// Fused kernel v4: 32x32x16 MFMA, K double-buffered, V triple-buffered,
// cross-chunk pipeline: iter c = { prefetch c+1; S[c]; PV[c-1]; tanh[c] }.
// ---------------------------------------------------------------------------
__global__ __launch_bounds__(256, 2) void fused_logits_mfma(
        const ushort* __restrict__ f1Wb, const ushort* __restrict__ f2b,
        const ushort* __restrict__ f1Wvb, const ushort* __restrict__ f2Wqb,
        const float* __restrict__ w_hv,  const float* __restrict__ w_hq,
        float* __restrict__ lo_v, float* __restrict__ lo_q) {
    __shared__ ushort KsU[2 * 32 * 256];  // swizzled: [row*256 + (c ^ ((row&15)<<3))]
    __shared__ ushort VtU[3 * 128 * 40];  // V^T [a][key], stride 40, 3 buffers

    const int tid  = threadIdx.x;
    const int lane = tid & 63;
    const int wid  = tid >> 6;
    const int l31  = lane & 31;
    const int h    = lane >> 5;
    const int h8   = h * 8;
    const int kxor = (l31 & 15) << 3;

    // XCD-aware decode: wg&7 = XCD; each XCD owns 4 complete batches
    const int wg   = blockIdx.x;
    const int xcd  = wg & 7;
    const int t    = wg >> 3;            // 0..63
    const int b    = xcd * 4 + (t >> 4);
    const int rem  = t & 15;
    const int z    = rem >> 3;
    const int r0   = (rem & 7) * 128;

    const ushort* Qb = z ? f2b   : f1Wb;
    const ushort* Kb = z ? f1Wb  : f2b;
    const ushort* Vg = z ? f1Wvb : f2Wqb;
    const ushort* Bg = z ? f2Wqb : f1Wvb;
    const float*  w  = z ? w_hq  : w_hv;
    float* logits    = z ? lo_q  : lo_v;

    // ---- Q fragments to registers (lane's own row, k-half h8)
    const int qrow = r0 + wid * 32 + l31;
    const ushort* qp = Qb + ((size_t)b * L_SEQ + qrow) * DDIM + h8;
    bf16x8 qf[16];
    #pragma unroll
    for (int st = 0; st < 16; ++st)
        qf[st] = *reinterpret_cast<const bf16x8*>(&qp[st * 16]);

    // per-lane swizzled source offsets for K staging
    int koff[4];
    #pragma unroll
    for (int it = 0; it < 4; ++it) {
        int rr  = wid * 8 + it * 2 + h;
        int col = (8 * l31) ^ ((rr & 15) << 3);
        koff[it] = rr * 256 + col;
    }
    // V gather coords (per thread, two slots)
    const int va0 = tid & 127,          vk0 = tid >> 7;
    const int va1 = (tid + 256) & 127,  vk1 = (tid + 256) >> 7;

    f32x16 acc[4];
    #pragma unroll
    for (int i = 0; i < 4; ++i)
        #pragma unroll
        for (int j = 0; j < 16; ++j) acc[i][j] = 0.f;

    uint4 vr0, vr1;
    bf16x8 pa0 = {}, pa1 = {};            // PV A-frags of previous chunk

    // ---- prologue: stage chunk 0 (K -> Kbuf0, V -> Vbuf0)
    {
        const ushort* gK = Kb + (size_t)b * L_SEQ * DDIM;
        #pragma unroll
        for (int it = 0; it < 4; ++it)
            async_copy16(&KsU[(wid * 8 + it * 2) * 256], gK + koff[it]);
        const ushort* gV = Vg + (size_t)b * L_SEQ * ADIM;
        union { uint4 v4; ushort us[8]; } u;
        const ushort* s0 = gV + (size_t)vk0 * 8 * ADIM + va0;
        #pragma unroll
        for (int j = 0; j < 8; ++j) u.us[j] = s0[(size_t)j * ADIM];
        vr0 = u.v4;
        const ushort* s1 = gV + (size_t)vk1 * 8 * ADIM + va1;
        #pragma unroll
        for (int j = 0; j < 8; ++j) u.us[j] = s1[(size_t)j * ADIM];
        vr1 = u.v4;
        *reinterpret_cast<uint4*>(&VtU[va0 * 40 + vk0 * 8]) = vr0;
        *reinterpret_cast<uint4*>(&VtU[va1 * 40 + vk1 * 8]) = vr1;
    }
    __syncthreads();

    for (int c = 0; c < 32; ++c) {
        const int kcur = c & 1;
        const ushort* Kc = &KsU[kcur * (32 * 256)];
        const bool more = (c + 1 < 32);

        // ---- prefetch chunk c+1 (K DMA + V gather to regs)
        if (more) {
            ushort* Kn = &KsU[(kcur ^ 1) * (32 * 256)];
            const ushort* gK = Kb + ((size_t)b * L_SEQ + (c + 1) * 32) * DDIM;
            #pragma unroll
            for (int it = 0; it < 4; ++it)
                async_copy16(&Kn[(wid * 8 + it * 2) * 256], gK + koff[it]);
            const ushort* gV = Vg + ((size_t)b * L_SEQ + (c + 1) * 32) * ADIM;
            union { uint4 v4; ushort us[8]; } u;
            const ushort* s0 = gV + (size_t)vk0 * 8 * ADIM + va0;
            #pragma unroll
            for (int j = 0; j < 8; ++j) u.us[j] = s0[(size_t)j * ADIM];
            vr0 = u.v4;
            const ushort* s1 = gV + (size_t)vk1 * 8 * ADIM + va1;
            #pragma unroll
            for (int j = 0; j < 8; ++j) u.us[j] = s1[(size_t)j * ADIM];
            vr1 = u.v4;
        }

        // ---- S^T = K . Q^T (chunk c): lane l31 = q-col, regs = keys
        f32x16 sA, sB;
        #pragma unroll
        for (int j = 0; j < 16; ++j) { sA[j] = 0.f; sB[j] = 0.f; }
        __builtin_amdgcn_s_setprio(1);
        #pragma unroll
        for (int st = 0; st < 8; ++st) {
            bf16x8 k0 = *reinterpret_cast<const bf16x8*>(
                &Kc[l31 * 256 + (((2 * st) * 16 + h8) ^ kxor)]);
            bf16x8 k1 = *reinterpret_cast<const bf16x8*>(
                &Kc[l31 * 256 + (((2 * st + 1) * 16 + h8) ^ kxor)]);
            sA = __builtin_amdgcn_mfma_f32_32x32x16_bf16(k0, qf[2 * st],     sA, 0, 0, 0);
            sB = __builtin_amdgcn_mfma_f32_32x32x16_bf16(k1, qf[2 * st + 1], sB, 0, 0, 0);
        }
        // ---- PV of chunk c-1 (pa from prev iter, V from buffer (c-1)%3)
        if (c > 0) {
            const ushort* Vp = &VtU[((c + 2) % 3) * (128 * 40)];
            #pragma unroll
            for (int nt = 0; nt < 4; ++nt) {
                bf16x8 vb0 = *reinterpret_cast<const bf16x8*>(&Vp[(nt * 32 + l31) * 40 + h8]);
                acc[nt] = __builtin_amdgcn_mfma_f32_32x32x16_bf16(pa0, vb0, acc[nt], 0, 0, 0);
            }
            #pragma unroll
            for (int nt = 0; nt < 4; ++nt) {
                bf16x8 vb1 = *reinterpret_cast<const bf16x8*>(&Vp[(nt * 32 + l31) * 40 + 16 + h8]);
                acc[nt] = __builtin_amdgcn_mfma_f32_32x32x16_bf16(pa1, vb1, acc[nt], 0, 0, 0);
            }
        }
        __builtin_amdgcn_s_setprio(0);

        // ---- tanh + pack chunk c -> pa0/pa1 (consumed next iteration)
        uint c0p = cvtpk_bf16(tanh_fast(sA[0]  + sB[0]),  tanh_fast(sA[1]  + sB[1]));
        uint c1p = cvtpk_bf16(tanh_fast(sA[2]  + sB[2]),  tanh_fast(sA[3]  + sB[3]));
        uint c2p = cvtpk_bf16(tanh_fast(sA[4]  + sB[4]),  tanh_fast(sA[5]  + sB[5]));
        uint c3p = cvtpk_bf16(tanh_fast(sA[6]  + sB[6]),  tanh_fast(sA[7]  + sB[7]));
        uint c4p = cvtpk_bf16(tanh_fast(sA[8]  + sB[8]),  tanh_fast(sA[9]  + sB[9]));
        uint c5p = cvtpk_bf16(tanh_fast(sA[10] + sB[10]), tanh_fast(sA[11] + sB[11]));
        uint c6p = cvtpk_bf16(tanh_fast(sA[12] + sB[12]), tanh_fast(sA[13] + sB[13]));
        uint c7p = cvtpk_bf16(tanh_fast(sA[14] + sB[14]), tanh_fast(sA[15] + sB[15]));
        asm("v_permlane32_swap_b32 %0, %1" : "+v"(c0p), "+v"(c2p));
        asm("v_permlane32_swap_b32 %0, %1" : "+v"(c1p), "+v"(c3p));
        asm("v_permlane32_swap_b32 %0, %1" : "+v"(c4p), "+v"(c6p));
        asm("v_permlane32_swap_b32 %0, %1" : "+v"(c5p), "+v"(c7p));
        union { uint u[4]; bf16x8 v; } pu0 = {{c0p, c1p, c2p, c3p}};
        union { uint u[4]; bf16x8 v; } pu1 = {{c4p, c5p, c6p, c7p}};
        pa0 = pu0.v; pa1 = pu1.v;

        // ---- land chunk c+1's V into buffer (c+1)%3
        if (more) {
            ushort* Vn = &VtU[((c + 1) % 3) * (128 * 40)];
            *reinterpret_cast<uint4*>(&Vn[va0 * 40 + vk0 * 8]) = vr0;
            *reinterpret_cast<uint4*>(&Vn[va1 * 40 + vk1 * 8]) = vr1;
        }
        __syncthreads();   // implicit vmcnt(0)+lgkmcnt(0)
    }

    // ---- final PV for chunk 31 (V in buffer 31%3 = 1)
    {
        const ushort* Vp = &VtU[(31 % 3) * (128 * 40)];
        #pragma unroll
        for (int nt = 0; nt < 4; ++nt) {
            bf16x8 vb0 = *reinterpret_cast<const bf16x8*>(&Vp[(nt * 32 + l31) * 40 + h8]);
            acc[nt] = __builtin_amdgcn_mfma_f32_32x32x16_bf16(pa0, vb0, acc[nt], 0, 0, 0);
        }
        #pragma unroll
        for (int nt = 0; nt < 4; ++nt) {
            bf16x8 vb1 = *reinterpret_cast<const bf16x8*>(&Vp[(nt * 32 + l31) * 40 + 16 + h8]);
            acc[nt] = __builtin_amdgcn_mfma_f32_32x32x16_bf16(pa1, vb1, acc[nt], 0, 0, 0);
        }
    }

    // ---- epilogue: lane holds O[row][col=nt*32+l31], rows (reg&3)+8*(reg>>2)+4h
    float wv[4];
    #pragma unroll
    for (int nt = 0; nt < 4; ++nt) wv[nt] = w[nt * 32 + l31];
    const size_t bbase = ((size_t)b * L_SEQ + r0) * ADIM;
    #pragma unroll
    for (int reg = 0; reg < 16; ++reg) {
        int rowl = (reg & 3) + 8 * (reg >> 2) + 4 * h;
        int row  = wid * 32 + rowl;
        float p = 0.f;
        #pragma unroll
        for (int nt = 0; nt < 4; ++nt) {
            float bias = bf2f(Bg[bbase + (size_t)row * ADIM + nt * 32 + l31]);
            p = fmaf(tanh_fast(bias + acc[nt][reg]), wv[nt], p);
        }
        p += __shfl_xor(p, 1);
        p += __shfl_xor(p, 2);
        p += __shfl_xor(p, 4);
        p += __shfl_xor(p, 8);
        p += __shfl_xor(p, 16);
        if (l31 == 0) logits[(size_t)b * L_SEQ + r0 + row] = p;
    }
}

// ---------------------------------------------------------------------------
// Faithful masked softmax + slice of attention-weighted row sum, merged.
// ---------------------------------------------------------------------------
__global__ __launch_bounds__(256) void softmax_wsum(
        const float* __restrict__ lo_v, const float* __restrict__ lo_q,
        const int* __restrict__ mask1,  const int* __restrict__ mask2,
        const float* __restrict__ f1,   const float* __restrict__ f2,
        float* __restrict__ partial) {
    __shared__ float rs[L_SEQ];
    __shared__ float red[256];
    const int tid = threadIdx.x;
    const int b   = blockIdx.x;
    const int sel = blockIdx.y;
    const int zz  = blockIdx.z;
    const float* logits = sel ? lo_q : lo_v;
    const int*   mask   = sel ? mask2 : mask1;

    float z[4], m[4];
    float lmax = -1e30f;
    #pragma unroll
    for (int i = 0; i < 4; ++i) {
        int l = i * 256 + tid;
        float lv = logits[(size_t)b * L_SEQ + l];
        m[i] = (float)mask[(size_t)b * L_SEQ + l];
        z[i] = lv * m[i];
        lmax = fmaxf(lmax, z[i]);
    }
    red[tid] = lmax; __syncthreads();
    for (int s = 128; s > 0; s >>= 1) {
        if (tid < s) red[tid] = fmaxf(red[tid], red[tid + s]);
        __syncthreads();
    }
    const float mx = red[0];
    __syncthreads();

    float p[4], lsum = 0.f;
    #pragma unroll
    for (int i = 0; i < 4; ++i) { p[i] = expf(z[i] - mx); lsum += p[i]; }
    red[tid] = lsum; __syncthreads();
    for (int s = 128; s > 0; s >>= 1) {
        if (tid < s) red[tid] += red[tid + s];
        __syncthreads();
    }
    const float Z = red[0];
    __syncthreads();

    float r[4], rsum = 0.f;
    #pragma unroll
    for (int i = 0; i < 4; ++i) { r[i] = (p[i] / Z) * m[i]; rsum += r[i]; }
    red[tid] = rsum; __syncthreads();
    for (int s = 128; s > 0; s >>= 1) {
        if (tid < s) red[tid] += red[tid + s];
        __syncthreads();
    }
    const float inv = 1.0f / (red[0] + 1e-13f);
    __syncthreads();

    #pragma unroll
    for (int i = 0; i < 4; ++i) rs[i * 256 + tid] = r[i] * inv;
    __syncthreads();

    // weighted sum over this block's l-slice; thread = output dim d
    const int l0 = zz * 128;
    const float* f  = sel ? f2 : f1;
    const float* fb = f + ((size_t)b * L_SEQ + l0) * DDIM + tid;
    float acc = 0.f;
    #pragma unroll 4
    for (int j = 0; j < 128; ++j)
        acc = fmaf(rs[l0 + j], fb[(size_t)j * DDIM], acc);
    partial[(((size_t)zz * 2 + sel) * NB + b) * DDIM + tid] = acc;
}

__global__ __launch_bounds__(256) void wsum_reduce(
        const float* __restrict__ partial, float* __restrict__ out) {
    const int tid = threadIdx.x;
    const int sb  = blockIdx.x;          // sel*NB + b
    float s = 0.f;
    #pragma unroll
    for (int zz = 0; zz < 8; ++zz)
        s += partial[((size_t)zz * 64 + sb) * DDIM + tid];
    out[(size_t)sb * DDIM + tid] = s;
}

// ---------------------------------------------------------------------------
extern "C" void kernel_launch(void* const* d_in, const int* in_sizes, int n_in,
                              void* d_out, int out_size, void* d_ws, size_t ws_size,
                              hipStream_t stream) {
    const float* f1    = (const float*)d_in[0];
    const float* f2    = (const float*)d_in[1];
    const int*   mask1 = (const int*)d_in[2];
    const int*   mask2 = (const int*)d_in[3];
    const float* W     = (const float*)d_in[4];
    const float* Wv    = (const float*)d_in[5];
    const float* Wq    = (const float*)d_in[6];
    const float* w_hv  = (const float*)d_in[7];
    const float* w_hq  = (const float*)d_in[8];
    float* out = (float*)d_out;

    // workspace layout (ushort units) ~50 MB total
    ushort* f2b   = (ushort*)d_ws;              // [32,1024,256] bf16
    ushort* f1Wb  = f2b   + 8388608;            // [32,1024,256] bf16
    ushort* f1Wvb = f1Wb  + 8388608;            // [32,1024,128] bf16
    ushort* f2Wqb = f1Wvb + 4194304;            // [32,1024,128] bf16
    ushort* WTh   = f2Wqb + 4194304;            // [256,256] hi then lo
    ushort* WvTh  = WTh   + 131072;             // [128,256] hi then lo
    ushort* WqTh  = WvTh  + 65536;              // [128,256] hi then lo
    float*  lo_v  = (float*)(WqTh + 65536);     // [32,1024]
    float*  lo_q  = lo_v + 32768;               // [32,1024]
    float*  part  = lo_q + 32768;               // [8,2,32,256]

    wt_prep<<<256, 256, 0, stream>>>(W, Wv, Wq, WTh, WvTh, WqTh);

    proj_all<<<2048, 256, 0, stream>>>(f1, f2, WTh, WvTh, WqTh,
                                       f1Wb, f1Wvb, f2Wqb, f2b);

    fused_logits_mfma<<<512, 256, 0, stream>>>(
        f1Wb, f2b, f1Wvb, f2Wqb, w_hv, w_hq, lo_v, lo_q);

    softmax_wsum<<<dim3(NB, 2, 8), 256, 0, stream>>>(
        lo_v, lo_q, mask1, mask2, f1, f2, part);
    wsum_reduce<<<64, 256, 0, stream>>>(part, out);
}

// Round 11
// 136.886 us; speedup vs baseline: 1.0482x; 1.0482x over previous
//
#include <hip/hip_runtime.h>
#include <math.h>

#define L_SEQ 1024
#define DDIM  256
#define ADIM  128
#define NB    32

typedef __attribute__((ext_vector_type(8))) short bf16x8;
typedef __attribute__((ext_vector_type(4))) float f32x4;
typedef __attribute__((ext_vector_type(16))) float f32x16;

__device__ __forceinline__ ushort f2bf(float x) {      // fp32 -> bf16 RNE
    uint u = __builtin_bit_cast(uint, x);
    u = (u + 0x7FFFu + ((u >> 16) & 1u)) >> 16;
    return (ushort)u;
}
__device__ __forceinline__ float bf2f(ushort h) {
    uint u = ((uint)h) << 16;
    return __builtin_bit_cast(float, u);
}
// tanh(x) = 1 - 2/(1+e^{2x}); exact at both saturations.
__device__ __forceinline__ float tanh_fast(float x) {
    float e = __expf(x * 2.0f);
    return fmaf(-2.0f, __builtin_amdgcn_rcpf(1.0f + e), 1.0f);
}
__device__ __forceinline__ uint cvtpk_bf16(float lo, float hi) {
    uint r;
    asm("v_cvt_pk_bf16_f32 %0, %1, %2" : "=v"(r) : "v"(lo), "v"(hi));
    return r;
}
// async global->LDS, 16B per lane; lds_dst wave-uniform, g_src per-lane
__device__ __forceinline__ void async_copy16(ushort* lds_dst, const ushort* g_src) {
    __builtin_amdgcn_global_load_lds(
        (const __attribute__((address_space(1))) unsigned int*)(g_src),
        (__attribute__((address_space(3))) unsigned int*)(lds_dst),
        16, 0, 0);
}
__device__ __forceinline__ void async_copy16f(float* lds_dst, const float* g_src) {
    __builtin_amdgcn_global_load_lds(
        (const __attribute__((address_space(1))) unsigned int*)(g_src),
        (__attribute__((address_space(3))) unsigned int*)(lds_dst),
        16, 0, 0);
}

// ---------------------------------------------------------------------------
// Weight prep: w [256, N] fp32 -> WT_h/WT_l [N, 256] bf16 (transpose + split)
// ---------------------------------------------------------------------------
__global__ __launch_bounds__(256) void wt_prep(
        const float* __restrict__ W,  const float* __restrict__ Wv,
        const float* __restrict__ Wq,
        ushort* __restrict__ WTh, ushort* __restrict__ WvTh,
        ushort* __restrict__ WqTh) {
    int k = blockIdx.x;
    int tid = threadIdx.x;
    #pragma unroll
    for (int t = tid; t < 512; t += 256) {
        const float* src; ushort* dh; int n, nn;
        if (t < 256)      { src = W;  dh = WTh;  n = t;       nn = 256; }
        else if (t < 384) { src = Wv; dh = WvTh; n = t - 256; nn = 128; }
        else              { src = Wq; dh = WqTh; n = t - 384; nn = 128; }
        ushort* dl = dh + (size_t)nn * 256;
        float x = src[(size_t)k * nn + n];
        ushort hh = f2bf(x);
        dh[(size_t)n * 256 + k] = hh;
        dl[(size_t)n * 256 + k] = f2bf(x - bf2f(hh));
    }
}

// ---------------------------------------------------------------------------
// All three projection GEMMs + f2 bf16 convert in one launch.
// W-proj blocks are n-major: bid<256 -> n0=0, bid in [256,512) -> n0=128 with
// the SAME m0 -- A-tile-sharing pairs (k, k+256) land on the same XCD
// (256 % 8 == 0), so f1 tiles hit L2 instead of refetching from HBM.
// ---------------------------------------------------------------------------
__global__ __launch_bounds__(256, 2) void proj_all(
        const float* __restrict__ f1, const float* __restrict__ f2,
        const ushort* __restrict__ WTh, const ushort* __restrict__ WvTh,
        const ushort* __restrict__ WqTh,
        ushort* __restrict__ f1Wb, ushort* __restrict__ f1Wvb,
        ushort* __restrict__ f2Wqb, ushort* __restrict__ f2b) {
    __shared__ float  As[128 * 64];
    __shared__ ushort Bs[128 * 128];

    const int bid = blockIdx.x;
    const int tid = threadIdx.x;

    if (bid >= 1024) {                       // f2 convert path (no barriers)
        const int base = (bid - 1024) * 8192;
        #pragma unroll
        for (int it = 0; it < 4; ++it) {
            int i = base + it * 2048 + tid * 8;
            float4 a = *reinterpret_cast<const float4*>(&f2[i]);
            float4 b = *reinterpret_cast<const float4*>(&f2[i + 4]);
            ushort4 lo = { f2bf(a.x), f2bf(a.y), f2bf(a.z), f2bf(a.w) };
            ushort4 hi = { f2bf(b.x), f2bf(b.y), f2bf(b.z), f2bf(b.w) };
            *reinterpret_cast<ushort4*>(&f2b[i]) = lo;
            *reinterpret_cast<ushort4*>(&f2b[i + 4]) = hi;
        }
        return;
    }

    const float* A; const ushort* BTh; ushort* C; int N, m0, n0;
    if (bid < 256)      { A = f1; BTh = WTh;  C = f1Wb;  N = 256; m0 = bid * 128;        n0 = 0;   }
    else if (bid < 512) { A = f1; BTh = WTh;  C = f1Wb;  N = 256; m0 = (bid - 256) * 128; n0 = 128; }
    else if (bid < 768) { A = f1; BTh = WvTh; C = f1Wvb; N = 128; m0 = (bid - 512) * 128; n0 = 0;   }
    else                { A = f2; BTh = WqTh; C = f2Wqb; N = 128; m0 = (bid - 768) * 128; n0 = 0;   }

    const int lane = tid & 63;
    const int wid  = tid >> 6;
    const int l31  = lane & 31;
    const int h    = lane >> 5;
    const int wrow = wid * 32;
    const int row  = wrow + l31;
    const int rsw  = row & 15;

    // per-lane staging source offsets (linear dest, inverse-swizzled source)
    int aoff[8], boff[8];
    #pragma unroll
    for (int it = 0; it < 8; ++it) {
        int idx = it * 256 + tid;
        int r   = idx >> 4, g = idx & 15;
        int gx  = g ^ (r & 15);
        aoff[it] = (m0 + r) * 256 + gx * 4;
        boff[it] = (n0 + r) * 256 + (gx & 7) * 8 + ((gx & 8) ? N * 256 : 0);
    }

    f32x16 acc[4];
    #pragma unroll
    for (int i = 0; i < 4; ++i)
        #pragma unroll
        for (int j = 0; j < 16; ++j) acc[i][j] = 0.f;

    for (int kc = 0; kc < 4; ++kc) {
        const int k0 = kc * 64;
        __syncthreads();
        #pragma unroll
        for (int it = 0; it < 8; ++it) {
            async_copy16f(&As[it * 1024 + wid * 256], A + aoff[it] + k0);
            async_copy16(&Bs[it * 2048 + wid * 512], BTh + boff[it] + k0);
        }
        __syncthreads();

        #pragma unroll
        for (int s = 0; s < 4; ++s) {
            int ga = s * 4 + h * 2;
            float4 alo = *reinterpret_cast<const float4*>(&As[(row * 16 + (ga ^ rsw)) * 4]);
            float4 ahi = *reinterpret_cast<const float4*>(&As[(row * 16 + ((ga + 1) ^ rsw)) * 4]);
            uint ah0 = cvtpk_bf16(alo.x, alo.y);
            uint ah1 = cvtpk_bf16(alo.z, alo.w);
            uint ah2 = cvtpk_bf16(ahi.x, ahi.y);
            uint ah3 = cvtpk_bf16(ahi.z, ahi.w);
            float r0 = alo.x - __builtin_bit_cast(float, ah0 << 16);
            float r1 = alo.y - __builtin_bit_cast(float, ah0 & 0xffff0000u);
            float r2 = alo.z - __builtin_bit_cast(float, ah1 << 16);
            float r3 = alo.w - __builtin_bit_cast(float, ah1 & 0xffff0000u);
            float r4 = ahi.x - __builtin_bit_cast(float, ah2 << 16);
            float r5 = ahi.y - __builtin_bit_cast(float, ah2 & 0xffff0000u);
            float r6 = ahi.z - __builtin_bit_cast(float, ah3 << 16);
            float r7 = ahi.w - __builtin_bit_cast(float, ah3 & 0xffff0000u);
            uint al0 = cvtpk_bf16(r0, r1), al1 = cvtpk_bf16(r2, r3);
            uint al2 = cvtpk_bf16(r4, r5), al3 = cvtpk_bf16(r6, r7);
            union { uint u[4]; bf16x8 v; } uh = {{ah0, ah1, ah2, ah3}};
            union { uint u[4]; bf16x8 v; } ul = {{al0, al1, al2, al3}};
            bf16x8 ah = uh.v, al = ul.v;

            #pragma unroll
            for (int nf = 0; nf < 4; ++nf) {
                int col = nf * 32 + l31;
                int csw = col & 15;
                int gb  = s * 2 + h;
                bf16x8 bh = *reinterpret_cast<const bf16x8*>(&Bs[col * 128 + (gb ^ csw) * 8]);
                bf16x8 bl = *reinterpret_cast<const bf16x8*>(&Bs[col * 128 + ((gb + 8) ^ csw) * 8]);
                acc[nf] = __builtin_amdgcn_mfma_f32_32x32x16_bf16(ah, bh, acc[nf], 0, 0, 0);
                acc[nf] = __builtin_amdgcn_mfma_f32_32x32x16_bf16(ah, bl, acc[nf], 0, 0, 0);
                acc[nf] = __builtin_amdgcn_mfma_f32_32x32x16_bf16(al, bh, acc[nf], 0, 0, 0);
            }
        }
    }

    #pragma unroll
    for (int nf = 0; nf < 4; ++nf)
        #pragma unroll
        for (int reg = 0; reg < 16; ++reg) {
            int rowl = (reg & 3) + 8 * (reg >> 2) + 4 * h;
            C[(size_t)(m0 + wrow + rowl) * N + n0 + nf * 32 + l31] = f2bf(acc[nf][reg]);
        }
}

// ---------------------------------------------------------------------------
// Fused kernel v5: 32x32x16 MFMA, K double-buffered, V triple-buffered.
// Iter c = { prefetch c+1; PV[c-1] (operands ready -> hides K ds_read
// latency); S[c]; tanh[c]; land V[c+1] }. One barrier per chunk.
// ---------------------------------------------------------------------------
__global__ __launch_bounds__(256, 2) void fused_logits_mfma(
        const ushort* __restrict__ f1Wb, const ushort* __restrict__ f2b,
        const ushort* __restrict__ f1Wvb, const ushort* __restrict__ f2Wqb,
        const float* __restrict__ w_hv,  const float* __restrict__ w_hq,
        float* __restrict__ lo_v, float* __restrict__ lo_q) {
    __shared__ ushort KsU[2 * 32 * 256];  // swizzled: [row*256 + (c ^ ((row&15)<<3))]
    __shared__ ushort VtU[3 * 128 * 40];  // V^T [a][key], stride 40, 3 buffers

    const int tid  = threadIdx.x;
    const int lane = tid & 63;
    const int wid  = tid >> 6;
    const int l31  = lane & 31;
    const int h    = lane >> 5;
    const int h8   = h * 8;
    const int kxor = (l31 & 15) << 3;

    // XCD-aware decode: wg&7 = XCD; each XCD owns 4 complete batches
    const int wg   = blockIdx.x;
    const int xcd  = wg & 7;
    const int t    = wg >> 3;            // 0..63
    const int b    = xcd * 4 + (t >> 4);
    const int rem  = t & 15;
    const int z    = rem >> 3;
    const int r0   = (rem & 7) * 128;

    const ushort* Qb = z ? f2b   : f1Wb;
    const ushort* Kb = z ? f1Wb  : f2b;
    const ushort* Vg = z ? f1Wvb : f2Wqb;
    const ushort* Bg = z ? f2Wqb : f1Wvb;
    const float*  w  = z ? w_hq  : w_hv;
    float* logits    = z ? lo_q  : lo_v;

    // ---- Q fragments to registers (lane's own row, k-half h8)
    const int qrow = r0 + wid * 32 + l31;
    const ushort* qp = Qb + ((size_t)b * L_SEQ + qrow) * DDIM + h8;
    bf16x8 qf[16];
    #pragma unroll
    for (int st = 0; st < 16; ++st)
        qf[st] = *reinterpret_cast<const bf16x8*>(&qp[st * 16]);

    // per-lane swizzled source offsets for K staging
    int koff[4];
    #pragma unroll
    for (int it = 0; it < 4; ++it) {
        int rr  = wid * 8 + it * 2 + h;
        int col = (8 * l31) ^ ((rr & 15) << 3);
        koff[it] = rr * 256 + col;
    }
    // V gather coords (per thread, two slots)
    const int va0 = tid & 127,          vk0 = tid >> 7;
    const int va1 = (tid + 256) & 127,  vk1 = (tid + 256) >> 7;

    f32x16 acc[4];
    #pragma unroll
    for (int i = 0; i < 4; ++i)
        #pragma unroll
        for (int j = 0; j < 16; ++j) acc[i][j] = 0.f;

    uint4 vr0, vr1;
    bf16x8 pa0 = {}, pa1 = {};            // PV A-frags of previous chunk

    // ---- prologue: stage chunk 0 (K -> Kbuf0, V -> Vbuf0)
    {
        const ushort* gK = Kb + (size_t)b * L_SEQ * DDIM;
        #pragma unroll
        for (int it = 0; it < 4; ++it)
            async_copy16(&KsU[(wid * 8 + it * 2) * 256], gK + koff[it]);
        const ushort* gV = Vg + (size_t)b * L_SEQ * ADIM;
        union { uint4 v4; ushort us[8]; } u;
        const ushort* s0 = gV + (size_t)vk0 * 8 * ADIM + va0;
        #pragma unroll
        for (int j = 0; j < 8; ++j) u.us[j] = s0[(size_t)j * ADIM];
        vr0 = u.v4;
        const ushort* s1 = gV + (size_t)vk1 * 8 * ADIM + va1;
        #pragma unroll
        for (int j = 0; j < 8; ++j) u.us[j] = s1[(size_t)j * ADIM];
        vr1 = u.v4;
        *reinterpret_cast<uint4*>(&VtU[va0 * 40 + vk0 * 8]) = vr0;
        *reinterpret_cast<uint4*>(&VtU[va1 * 40 + vk1 * 8]) = vr1;
    }
    __syncthreads();

    for (int c = 0; c < 32; ++c) {
        const int kcur = c & 1;
        const ushort* Kc = &KsU[kcur * (32 * 256)];
        const bool more = (c + 1 < 32);

        // ---- prefetch chunk c+1 (K DMA + V gather to regs)
        if (more) {
            ushort* Kn = &KsU[(kcur ^ 1) * (32 * 256)];
            const ushort* gK = Kb + ((size_t)b * L_SEQ + (c + 1) * 32) * DDIM;
            #pragma unroll
            for (int it = 0; it < 4; ++it)
                async_copy16(&Kn[(wid * 8 + it * 2) * 256], gK + koff[it]);
            const ushort* gV = Vg + ((size_t)b * L_SEQ + (c + 1) * 32) * ADIM;
            union { uint4 v4; ushort us[8]; } u;
            const ushort* s0 = gV + (size_t)vk0 * 8 * ADIM + va0;
            #pragma unroll
            for (int j = 0; j < 8; ++j) u.us[j] = s0[(size_t)j * ADIM];
            vr0 = u.v4;
            const ushort* s1 = gV + (size_t)vk1 * 8 * ADIM + va1;
            #pragma unroll
            for (int j = 0; j < 8; ++j) u.us[j] = s1[(size_t)j * ADIM];
            vr1 = u.v4;
        }

        __builtin_amdgcn_s_setprio(1);
        // ---- PV of chunk c-1 FIRST: operands (pa regs, V in LDS) are ready,
        // these 8 MFMAs hide the K ds_read latency of S[c] below.
        if (c > 0) {
            const ushort* Vp = &VtU[((c + 2) % 3) * (128 * 40)];
            #pragma unroll
            for (int nt = 0; nt < 4; ++nt) {
                bf16x8 vb0 = *reinterpret_cast<const bf16x8*>(&Vp[(nt * 32 + l31) * 40 + h8]);
                acc[nt] = __builtin_amdgcn_mfma_f32_32x32x16_bf16(pa0, vb0, acc[nt], 0, 0, 0);
            }
            #pragma unroll
            for (int nt = 0; nt < 4; ++nt) {
                bf16x8 vb1 = *reinterpret_cast<const bf16x8*>(&Vp[(nt * 32 + l31) * 40 + 16 + h8]);
                acc[nt] = __builtin_amdgcn_mfma_f32_32x32x16_bf16(pa1, vb1, acc[nt], 0, 0, 0);
            }
        }

        // ---- S^T = K . Q^T (chunk c): lane l31 = q-col, regs = keys
        f32x16 sA, sB;
        #pragma unroll
        for (int j = 0; j < 16; ++j) { sA[j] = 0.f; sB[j] = 0.f; }
        #pragma unroll
        for (int st = 0; st < 8; ++st) {
            bf16x8 k0 = *reinterpret_cast<const bf16x8*>(
                &Kc[l31 * 256 + (((2 * st) * 16 + h8) ^ kxor)]);
            bf16x8 k1 = *reinterpret_cast<const bf16x8*>(
                &Kc[l31 * 256 + (((2 * st + 1) * 16 + h8) ^ kxor)]);
            sA = __builtin_amdgcn_mfma_f32_32x32x16_bf16(k0, qf[2 * st],     sA, 0, 0, 0);
            sB = __builtin_amdgcn_mfma_f32_32x32x16_bf16(k1, qf[2 * st + 1], sB, 0, 0, 0);
        }
        __builtin_amdgcn_s_setprio(0);

        // ---- tanh + pack chunk c -> pa0/pa1 (consumed next iteration)
        uint c0p = cvtpk_bf16(tanh_fast(sA[0]  + sB[0]),  tanh_fast(sA[1]  + sB[1]));
        uint c1p = cvtpk_bf16(tanh_fast(sA[2]  + sB[2]),  tanh_fast(sA[3]  + sB[3]));
        uint c2p = cvtpk_bf16(tanh_fast(sA[4]  + sB[4]),  tanh_fast(sA[5]  + sB[5]));
        uint c3p = cvtpk_bf16(tanh_fast(sA[6]  + sB[6]),  tanh_fast(sA[7]  + sB[7]));
        uint c4p = cvtpk_bf16(tanh_fast(sA[8]  + sB[8]),  tanh_fast(sA[9]  + sB[9]));
        uint c5p = cvtpk_bf16(tanh_fast(sA[10] + sB[10]), tanh_fast(sA[11] + sB[11]));
        uint c6p = cvtpk_bf16(tanh_fast(sA[12] + sB[12]), tanh_fast(sA[13] + sB[13]));
        uint c7p = cvtpk_bf16(tanh_fast(sA[14] + sB[14]), tanh_fast(sA[15] + sB[15]));
        asm("v_permlane32_swap_b32 %0, %1" : "+v"(c0p), "+v"(c2p));
        asm("v_permlane32_swap_b32 %0, %1" : "+v"(c1p), "+v"(c3p));
        asm("v_permlane32_swap_b32 %0, %1" : "+v"(c4p), "+v"(c6p));
        asm("v_permlane32_swap_b32 %0, %1" : "+v"(c5p), "+v"(c7p));
        union { uint u[4]; bf16x8 v; } pu0 = {{c0p, c1p, c2p, c3p}};
        union { uint u[4]; bf16x8 v; } pu1 = {{c4p, c5p, c6p, c7p}};
        pa0 = pu0.v; pa1 = pu1.v;

        // ---- land chunk c+1's V into buffer (c+1)%3
        if (more) {
            ushort* Vn = &VtU[((c + 1) % 3) * (128 * 40)];
            *reinterpret_cast<uint4*>(&Vn[va0 * 40 + vk0 * 8]) = vr0;
            *reinterpret_cast<uint4*>(&Vn[va1 * 40 + vk1 * 8]) = vr1;
        }
        __syncthreads();   // implicit vmcnt(0)+lgkmcnt(0)
    }

    // ---- final PV for chunk 31 (V in buffer 31%3 = 1)
    {
        const ushort* Vp = &VtU[(31 % 3) * (128 * 40)];
        #pragma unroll
        for (int nt = 0; nt < 4; ++nt) {
            bf16x8 vb0 = *reinterpret_cast<const bf16x8*>(&Vp[(nt * 32 + l31) * 40 + h8]);
            acc[nt] = __builtin_amdgcn_mfma_f32_32x32x16_bf16(pa0, vb0, acc[nt], 0, 0, 0);
        }
        #pragma unroll
        for (int nt = 0; nt < 4; ++nt) {
            bf16x8 vb1 = *reinterpret_cast<const bf16x8*>(&Vp[(nt * 32 + l31) * 40 + 16 + h8]);
            acc[nt] = __builtin_amdgcn_mfma_f32_32x32x16_bf16(pa1, vb1, acc[nt], 0, 0, 0);
        }
    }

    // ---- epilogue: lane holds O[row][col=nt*32+l31], rows (reg&3)+8*(reg>>2)+4h
    float wv[4];
    #pragma unroll
    for (int nt = 0; nt < 4; ++nt) wv[nt] = w[nt * 32 + l31];
    const size_t bbase = ((size_t)b * L_SEQ + r0) * ADIM;
    #pragma unroll
    for (int reg = 0; reg < 16; ++reg) {
        int rowl = (reg & 3) + 8 * (reg >> 2) + 4 * h;
        int row  = wid * 32 + rowl;
        float p = 0.f;
        #pragma unroll
        for (int nt = 0; nt < 4; ++nt) {
            float bias = bf2f(Bg[bbase + (size_t)row * ADIM + nt * 32 + l31]);
            p = fmaf(tanh_fast(bias + acc[nt][reg]), wv[nt], p);
        }
        p += __shfl_xor(p, 1);
        p += __shfl_xor(p, 2);
        p += __shfl_xor(p, 4);
        p += __shfl_xor(p, 8);
        p += __shfl_xor(p, 16);
        if (l31 == 0) logits[(size_t)b * L_SEQ + r0 + row] = p;
    }
}

// ---------------------------------------------------------------------------
// Faithful masked softmax + slice of attention-weighted row sum, merged.
// ---------------------------------------------------------------------------
__global__ __launch_bounds__(256) void softmax_wsum(
        const float* __restrict__ lo_v, const float* __restrict__ lo_q,
        const int* __restrict__ mask1,  const int* __restrict__ mask2,
        const float* __restrict__ f1,   const float* __restrict__ f2,
        float* __restrict__ partial) {
    __shared__ float rs[L_SEQ];
    __shared__ float red[256];
    const int tid = threadIdx.x;
    const int b   = blockIdx.x;
    const int sel = blockIdx.y;
    const int zz  = blockIdx.z;
    const float* logits = sel ? lo_q : lo_v;
    const int*   mask   = sel ? mask2 : mask1;

    float z[4], m[4];
    float lmax = -1e30f;
    #pragma unroll
    for (int i = 0; i < 4; ++i) {
        int l = i * 256 + tid;
        float lv = logits[(size_t)b * L_SEQ + l];
        m[i] = (float)mask[(size_t)b * L_SEQ + l];
        z[i] = lv * m[i];
        lmax = fmaxf(lmax, z[i]);
    }
    red[tid] = lmax; __syncthreads();
    for (int s = 128; s > 0; s >>= 1) {
        if (tid < s) red[tid] = fmaxf(red[tid], red[tid + s]);
        __syncthreads();
    }
    const float mx = red[0];
    __syncthreads();

    float p[4], lsum = 0.f;
    #pragma unroll
    for (int i = 0; i < 4; ++i) { p[i] = expf(z[i] - mx); lsum += p[i]; }
    red[tid] = lsum; __syncthreads();
    for (int s = 128; s > 0; s >>= 1) {
        if (tid < s) red[tid] += red[tid + s];
        __syncthreads();
    }
    const float Z = red[0];
    __syncthreads();

    float r[4], rsum = 0.f;
    #pragma unroll
    for (int i = 0; i < 4; ++i) { r[i] = (p[i] / Z) * m[i]; rsum += r[i]; }
    red[tid] = rsum; __syncthreads();
    for (int s = 128; s > 0; s >>= 1) {
        if (tid < s) red[tid] += red[tid + s];
        __syncthreads();
    }
    const float inv = 1.0f / (red[0] + 1e-13f);
    __syncthreads();

    #pragma unroll
    for (int i = 0; i < 4; ++i) rs[i * 256 + tid] = r[i] * inv;
    __syncthreads();

    // weighted sum over this block's l-slice; thread = output dim d
    const int l0 = zz * 128;
    const float* f  = sel ? f2 : f1;
    const float* fb = f + ((size_t)b * L_SEQ + l0) * DDIM + tid;
    float acc = 0.f;
    #pragma unroll 4
    for (int j = 0; j < 128; ++j)
        acc = fmaf(rs[l0 + j], fb[(size_t)j * DDIM], acc);
    partial[(((size_t)zz * 2 + sel) * NB + b) * DDIM + tid] = acc;
}

__global__ __launch_bounds__(256) void wsum_reduce(
        const float* __restrict__ partial, float* __restrict__ out) {
    const int tid = threadIdx.x;
    const int sb  = blockIdx.x;          // sel*NB + b
    float s = 0.f;
    #pragma unroll
    for (int zz = 0; zz < 8; ++zz)
        s += partial[((size_t)zz * 64 + sb) * DDIM + tid];
    out[(size_t)sb * DDIM + tid] = s;
}

// ---------------------------------------------------------------------------
extern "C" void kernel_launch(void* const* d_in, const int* in_sizes, int n_in,
                              void* d_out, int out_size, void* d_ws, size_t ws_size,
                              hipStream_t stream) {
    const float* f1    = (const float*)d_in[0];
    const float* f2    = (const float*)d_in[1];
    const int*   mask1 = (const int*)d_in[2];
    const int*   mask2 = (const int*)d_in[3];
    const float* W     = (const float*)d_in[4];
    const float* Wv    = (const float*)d_in[5];
    const float* Wq    = (const float*)d_in[6];
    const float* w_hv  = (const float*)d_in[7];
    const float* w_hq  = (const float*)d_in[8];
    float* out = (float*)d_out;

    // workspace layout (ushort units) ~50 MB total
    ushort* f2b   = (ushort*)d_ws;              // [32,1024,256] bf16
    ushort* f1Wb  = f2b   + 8388608;            // [32,1024,256] bf16
    ushort* f1Wvb = f1Wb  + 8388608;            // [32,1024,128] bf16
    ushort* f2Wqb = f1Wvb + 4194304;            // [32,1024,128] bf16
    ushort* WTh   = f2Wqb + 4194304;            // [256,256] hi then lo
    ushort* WvTh  = WTh   + 131072;             // [128,256] hi then lo
    ushort* WqTh  = WvTh  + 65536;              // [128,256] hi then lo
    float*  lo_v  = (float*)(WqTh + 65536);     // [32,1024]
    float*  lo_q  = lo_v + 32768;               // [32,1024]
    float*  part  = lo_q + 32768;               // [8,2,32,256]

    wt_prep<<<256, 256, 0, stream>>>(W, Wv, Wq, WTh, WvTh, WqTh);

    proj_all<<<2048, 256, 0, stream>>>(f1, f2, WTh, WvTh, WqTh,
                                       f1Wb, f1Wvb, f2Wqb, f2b);

    fused_logits_mfma<<<512, 256, 0, stream>>>(
        f1Wb, f2b, f1Wvb, f2Wqb, w_hv, w_hq, lo_v, lo_q);

    softmax_wsum<<<dim3(NB, 2, 8), 256, 0, stream>>>(
        lo_v, lo_q, mask1, mask2, f1, f2, part);
    wsum_reduce<<<64, 256, 0, stream>>>(part, out);
}